// Round 13
// baseline (258.872 us; speedup 1.0000x reference)
//
#include <hip/hip_runtime.h>

#define NB 4
#define NC 256
#define NHW 4096
#define NW 64
#define NTOPK 100
#define FMARGIN 4.1f

typedef float f32x4 __attribute__((ext_vector_type(4)));

__device__ __forceinline__ unsigned int tokey(float f) {
    unsigned int u = __float_as_uint(f);
    return (u & 0x80000000u) ? ~u : (u | 0x80000000u);
}
__device__ __forceinline__ float k16tof(unsigned int k) {
    unsigned int k32 = k << 16;
    return __uint_as_float((k32 & 0x80000000u) ? (k32 ^ 0x80000000u) : ~k32);
}

// ---- positive-pair (anchor) selection from the TPS grid ----
__global__ void k_anchor(const float* __restrict__ G, int* __restrict__ ac_flat,
                         int* __restrict__ pvalid) {
    int t = blockIdx.x * 256 + threadIdx.x;
    int b = t >> 12, p = t & (NHW - 1);
    float gxv = G[((size_t)b * NHW + p) * 2 + 0] * 64.0f;
    float gyv = G[((size_t)b * NHW + p) * 2 + 1] * 64.0f;
    float x0 = floorf(gxv), y0 = floorf(gyv);
    float cx[4] = {x0, x0 + 1.f, x0 + 1.f, x0};
    float cy[4] = {y0, y0, y0 + 1.f, y0 + 1.f};
    float d[4]; bool v[4]; float maxd = -INFINITY; bool any = false;
    #pragma unroll
    for (int i = 0; i < 4; ++i) {
        float dx = gxv - cx[i], dy = gyv - cy[i];
        d[i] = sqrtf(dx * dx + dy * dy);
        v[i] = (cx[i] >= 0.f) && (cy[i] >= 0.f) && (cx[i] <= 63.f) && (cy[i] <= 63.f);
        any = any || v[i];
        maxd = fmaxf(maxd, d[i]);
    }
    int sel = 0; float best = -INFINITY;
    #pragma unroll
    for (int i = 0; i < 4; ++i) {
        float prob = v[i] ? ((maxd + 0.3f) - d[i]) : -INFINITY;
        if (prob > best) { best = prob; sel = i; }
    }
    int acx = (int)cx[sel], acy = (int)cy[sel];
    int af = acy * NW + acx;
    af = af < 0 ? 0 : (af > NHW - 1 ? NHW - 1 : af);
    ac_flat[t] = af;
    pvalid[t] = any ? 1 : 0;
}

// ---- fused norm + transpose: sk -> skT[b][q][c] fp8 e4m3 ----
__global__ void k_packA(const float* __restrict__ sk, unsigned char* __restrict__ skT) {
    __shared__ float tile[64][NC + 1];
    __shared__ float psum[4][64];
    __shared__ float invs[64];
    const int blk = blockIdx.x;
    const int b = blk >> 6;
    const int q0 = (blk & 63) << 6;
    const int t = threadIdx.x;
    const int qloc = t & 63;
    const int c0 = t >> 6;
    const float* base = sk + (size_t)b * NC * NHW + q0 + qloc;
    #pragma unroll 8
    for (int cc = 0; cc < NC; cc += 4) {
        int c = cc + c0;
        tile[qloc][c] = base[(size_t)c * NHW];
    }
    __syncthreads();
    {
        float s = 0.f;
        #pragma unroll 8
        for (int j = 0; j < 64; ++j) { float v = tile[qloc][c0 * 64 + j]; s = fmaf(v, v, s); }
        psum[c0][qloc] = s;
    }
    __syncthreads();
    if (t < 64)
        invs[t] = 1.f / fmaxf(sqrtf(psum[0][t] + psum[1][t] + psum[2][t] + psum[3][t]), 1e-8f);
    __syncthreads();
    const int row = t >> 2, seg = (t & 3) * 64;
    const float iv = invs[row];
    unsigned char* out = skT + ((size_t)b * NHW + q0 + row) * NC + seg;
    #pragma unroll
    for (int j0 = 0; j0 < 64; j0 += 8) {
        unsigned int r0 = 0u, r1 = 0u;
        r0 = __builtin_amdgcn_cvt_pk_fp8_f32(tile[row][seg + j0 + 0] * iv, tile[row][seg + j0 + 1] * iv, r0, false);
        r0 = __builtin_amdgcn_cvt_pk_fp8_f32(tile[row][seg + j0 + 2] * iv, tile[row][seg + j0 + 3] * iv, r0, true);
        r1 = __builtin_amdgcn_cvt_pk_fp8_f32(tile[row][seg + j0 + 4] * iv, tile[row][seg + j0 + 5] * iv, r1, false);
        r1 = __builtin_amdgcn_cvt_pk_fp8_f32(tile[row][seg + j0 + 6] * iv, tile[row][seg + j0 + 7] * iv, r1, true);
        *(uint2*)(out + j0) = make_uint2(r0, r1);
    }
}

// ---- fused norm + pack: rf -> MFMA B layout refP[b][qt][kt][lane][8] fp8 ----
__global__ void k_packB(const float* __restrict__ rf, unsigned char* __restrict__ refP) {
    __shared__ float tile[64][NC + 1];
    __shared__ float psum[4][64];
    __shared__ float invs[64];
    const int blk = blockIdx.x;
    const int b = blk >> 6;
    const int q0 = (blk & 63) << 6;
    const int t = threadIdx.x;
    const int qloc = t & 63;
    const int c0 = t >> 6;
    const float* base = rf + (size_t)b * NC * NHW + q0 + qloc;
    #pragma unroll 8
    for (int cc = 0; cc < NC; cc += 4) {
        int c = cc + c0;
        tile[qloc][c] = base[(size_t)c * NHW];
    }
    __syncthreads();
    {
        float s = 0.f;
        #pragma unroll 8
        for (int j = 0; j < 64; ++j) { float v = tile[qloc][c0 * 64 + j]; s = fmaf(v, v, s); }
        psum[c0][qloc] = s;
    }
    __syncthreads();
    if (t < 64)
        invs[t] = 1.f / fmaxf(sqrtf(psum[0][t] + psum[1][t] + psum[2][t] + psum[3][t]), 1e-8f);
    __syncthreads();
    #pragma unroll
    for (int it = 0; it < 8; ++it) {
        int slot = it * 256 + t;
        int qt = slot >> 9;
        int kt = (slot >> 6) & 7;
        int lane = slot & 63;
        int g = lane >> 4, qll = lane & 15;
        int ql2 = (qt << 4) + qll;
        int c = kt * 32 + g * 8;
        const float iv = invs[ql2];
        unsigned int r0 = 0u, r1 = 0u;
        r0 = __builtin_amdgcn_cvt_pk_fp8_f32(tile[ql2][c + 0] * iv, tile[ql2][c + 1] * iv, r0, false);
        r0 = __builtin_amdgcn_cvt_pk_fp8_f32(tile[ql2][c + 2] * iv, tile[ql2][c + 3] * iv, r0, true);
        r1 = __builtin_amdgcn_cvt_pk_fp8_f32(tile[ql2][c + 4] * iv, tile[ql2][c + 5] * iv, r1, false);
        r1 = __builtin_amdgcn_cvt_pk_fp8_f32(tile[ql2][c + 6] * iv, tile[ql2][c + 7] * iv, r1, true);
        size_t oidx = (((size_t)(b * 256 + (q0 >> 4) + qt) * 8 + kt) * 64 + lane) * 8;
        *(uint2*)(refP + oidx) = make_uint2(r0, r1);
    }
}

// ---- fused FP8-MFMA cos + two-half selection; 74.8 KB LDS -> 2 blocks/CU ----
// Half 0: build keys (64 KB), exact per-half top-100 -> candL (packed key<<12|col).
// Half 1: rebuild keys in the same buffer, ONE tie-free 26-bit packed search
// over {half-1 keys + half-0 candidates}, then filter+sum. No waves_per_eu cap
// (its max=4 would forbid the 2nd resident block).
__global__ __launch_bounds__(1024) void k_main(
    const unsigned char* __restrict__ refP, const unsigned char* __restrict__ skT,
    const float* __restrict__ G,
    const int* __restrict__ ac_flat, const int* __restrict__ pvalid,
    float* __restrict__ row_val, int* __restrict__ row_valid)
{
    __shared__ unsigned int key2[8][2048];                   // 64 KB (one half)
    __shared__ __align__(16) unsigned char ancsA[8][64][8];  // 4 KB
    __shared__ unsigned int candL[16][NTOPK];                // 6.4 KB
    __shared__ float cpp[16];

    const int tid = threadIdx.x;
    const int lane = tid & 63;
    const int w = tid >> 6;      // wave 0..15 owns row w
    const int g = lane >> 4;
    const int ql = lane & 15;
    const int lblk = (blockIdx.x & 7) * 128 + (blockIdx.x >> 3);  // XCD swizzle
    const int b = lblk >> 8;
    const int p0 = (lblk & 255) << 4;

    // ---- phase A: anchors (fp8) ----
    {
        const int a = ac_flat[b * NHW + p0 + w];
        const unsigned char* src = skT + ((size_t)b * NHW + a) * NC;
        unsigned int v = *(const unsigned int*)(src + lane * 4);
        const int c = lane * 4;
        const int kk = c >> 5, gg = (c >> 3) & 3, j = c & 7;
        *(unsigned int*)&ancsA[kk][gg * 16 + w][j] = v;
    }
    __syncthreads();

    const int dhalf = p0 >> 11;                 // half containing the diagonal
    const int wstar = (p0 & 2047) >> 7;         // wave owning diag tile in-half
    const int tstar = (p0 >> 4) & 7;            // tile index within that wave
    const int rp = w >> 1;
    const int par = w & 1;

    long long af0 = *(const long long*)&ancsA[0][lane][0];
    long long af1 = *(const long long*)&ancsA[1][lane][0];
    long long af2 = *(const long long*)&ancsA[2][lane][0];
    long long af3 = *(const long long*)&ancsA[3][lane][0];
    long long af4 = *(const long long*)&ancsA[4][lane][0];
    long long af5 = *(const long long*)&ancsA[5][lane][0];
    long long af6 = *(const long long*)&ancsA[6][lane][0];
    long long af7 = *(const long long*)&ancsA[7][lane][0];

    // ============ HALF 0: GEMM (cols 0..2047) ============
    #pragma unroll
    for (int t = 0; t < 8; ++t) {
        f32x4 a4 = (f32x4){0.f, 0.f, 0.f, 0.f};
        const unsigned char* bpt =
            refP + (((size_t)(b * 256 + w * 8 + t) * 8) * 64 + lane) * 8;
        a4 = __builtin_amdgcn_mfma_f32_16x16x32_fp8_fp8(af0, *(const long long*)(bpt + 0 * 512), a4, 0, 0, 0);
        a4 = __builtin_amdgcn_mfma_f32_16x16x32_fp8_fp8(af1, *(const long long*)(bpt + 1 * 512), a4, 0, 0, 0);
        a4 = __builtin_amdgcn_mfma_f32_16x16x32_fp8_fp8(af2, *(const long long*)(bpt + 2 * 512), a4, 0, 0, 0);
        a4 = __builtin_amdgcn_mfma_f32_16x16x32_fp8_fp8(af3, *(const long long*)(bpt + 3 * 512), a4, 0, 0, 0);
        a4 = __builtin_amdgcn_mfma_f32_16x16x32_fp8_fp8(af4, *(const long long*)(bpt + 4 * 512), a4, 0, 0, 0);
        a4 = __builtin_amdgcn_mfma_f32_16x16x32_fp8_fp8(af5, *(const long long*)(bpt + 5 * 512), a4, 0, 0, 0);
        a4 = __builtin_amdgcn_mfma_f32_16x16x32_fp8_fp8(af6, *(const long long*)(bpt + 6 * 512), a4, 0, 0, 0);
        a4 = __builtin_amdgcn_mfma_f32_16x16x32_fp8_fp8(af7, *(const long long*)(bpt + 7 * 512), a4, 0, 0, 0);
        if (dhalf == 0 && w == wstar && t == tstar) {
            #pragma unroll
            for (int i = 0; i < 4; ++i)
                if (ql == g * 4 + i) cpp[g * 4 + i] = a4[i];
        }
        unsigned int k01 = (tokey(a4[0]) >> 16) | ((tokey(a4[1]) >> 16) << 16);
        unsigned int k23 = (tokey(a4[2]) >> 16) | ((tokey(a4[3]) >> 16) << 16);
        const int ctl = w * 8 + t;                 // local col-tile 0..127
        const int l_r = ctl >> 1;
        const int qd = ((ctl & 1) << 2) | (ql >> 2);
        const int pidx = (l_r << 5) + (((qd ^ (l_r & 7))) << 2) + (ql & 3);
        key2[2 * g + 0][pidx] = k01;
        key2[2 * g + 1][pidx] = k23;
    }
    __syncthreads();

    // ---- sel0: exact top-100 of half 0 -> candL[w] (packed key<<12|col) ----
    {
        unsigned int ku[32];   // ku[qd*4+e] = key for col lane*32 + qd*4 + e
        #pragma unroll
        for (int qd = 0; qd < 8; ++qd) {
            const uint4 v = *(const uint4*)&key2[rp][(lane << 5) + ((qd ^ (lane & 7)) << 2)];
            ku[4 * qd + 0] = par ? (v.x >> 16) : (v.x & 0xFFFFu);
            ku[4 * qd + 1] = par ? (v.y >> 16) : (v.y & 0xFFFFu);
            ku[4 * qd + 2] = par ? (v.z >> 16) : (v.z & 0xFFFFu);
            ku[4 * qd + 3] = par ? (v.w >> 16) : (v.w & 0xFFFFu);
        }
        unsigned int Ks = 0x4000u;
        #pragma unroll 1
        for (int bit = 14; bit >= 0; --bit) {
            const unsigned int T = Ks | (1u << bit);
            int c = 0;
            #pragma unroll
            for (int j = 0; j < 32; ++j)
                c += __popcll(__ballot(ku[j] < T));
            if (c < NTOPK) Ks = T;
        }
        int below = 0;
        #pragma unroll
        for (int j = 0; j < 32; ++j)
            below += __popcll(__ballot(ku[j] < Ks));
        const int tk = NTOPK - below;

        unsigned int tmask = 0u; int ltc = 0, nlt = 0;
        #pragma unroll
        for (int j = 0; j < 32; ++j) {
            if (ku[j] < Ks) nlt++;
            else if (ku[j] == Ks) { tmask |= (1u << j); ltc++; }
        }
        // exclusive lane-prefix of tie counts (col order = (lane, j) lex)
        int tpfx = ltc;
        #pragma unroll
        for (int d = 1; d < 64; d <<= 1) {
            int t2 = __shfl_up(tpfx, d, 64);
            if (lane >= d) tpfx += t2;
        }
        tpfx -= ltc;
        const int ekc = max(0, min(tk - tpfx, ltc));   // accepted ties this lane
        // exclusive lane-prefix of accepted counts -> write base
        int acc = nlt + ekc;
        int wbase = acc;
        #pragma unroll
        for (int d = 1; d < 64; d <<= 1) {
            int t2 = __shfl_up(wbase, d, 64);
            if (lane >= d) wbase += t2;
        }
        wbase -= acc;
        int idx = 0, mt = 0;
        #pragma unroll
        for (int j = 0; j < 32; ++j) {
            bool take = false;
            if (ku[j] < Ks) take = true;
            else if (ku[j] == Ks) { take = (mt < ekc); mt++; }
            if (take) {
                candL[w][wbase + idx] = (ku[j] << 12) | (unsigned)((lane << 5) + j);
                idx++;
            }
        }
    }
    __syncthreads();

    // ============ HALF 1: GEMM (cols 2048..4095) ============
    #pragma unroll
    for (int t = 0; t < 8; ++t) {
        f32x4 a4 = (f32x4){0.f, 0.f, 0.f, 0.f};
        const unsigned char* bpt =
            refP + (((size_t)(b * 256 + 128 + w * 8 + t) * 8) * 64 + lane) * 8;
        a4 = __builtin_amdgcn_mfma_f32_16x16x32_fp8_fp8(af0, *(const long long*)(bpt + 0 * 512), a4, 0, 0, 0);
        a4 = __builtin_amdgcn_mfma_f32_16x16x32_fp8_fp8(af1, *(const long long*)(bpt + 1 * 512), a4, 0, 0, 0);
        a4 = __builtin_amdgcn_mfma_f32_16x16x32_fp8_fp8(af2, *(const long long*)(bpt + 2 * 512), a4, 0, 0, 0);
        a4 = __builtin_amdgcn_mfma_f32_16x16x32_fp8_fp8(af3, *(const long long*)(bpt + 3 * 512), a4, 0, 0, 0);
        a4 = __builtin_amdgcn_mfma_f32_16x16x32_fp8_fp8(af4, *(const long long*)(bpt + 4 * 512), a4, 0, 0, 0);
        a4 = __builtin_amdgcn_mfma_f32_16x16x32_fp8_fp8(af5, *(const long long*)(bpt + 5 * 512), a4, 0, 0, 0);
        a4 = __builtin_amdgcn_mfma_f32_16x16x32_fp8_fp8(af6, *(const long long*)(bpt + 6 * 512), a4, 0, 0, 0);
        a4 = __builtin_amdgcn_mfma_f32_16x16x32_fp8_fp8(af7, *(const long long*)(bpt + 7 * 512), a4, 0, 0, 0);
        if (dhalf == 1 && w == wstar && t == tstar) {
            #pragma unroll
            for (int i = 0; i < 4; ++i)
                if (ql == g * 4 + i) cpp[g * 4 + i] = a4[i];
        }
        unsigned int k01 = (tokey(a4[0]) >> 16) | ((tokey(a4[1]) >> 16) << 16);
        unsigned int k23 = (tokey(a4[2]) >> 16) | ((tokey(a4[3]) >> 16) << 16);
        const int ctl = w * 8 + t;
        const int l_r = ctl >> 1;
        const int qd = ((ctl & 1) << 2) | (ql >> 2);
        const int pidx = (l_r << 5) + (((qd ^ (l_r & 7))) << 2) + (ql & 3);
        key2[2 * g + 0][pidx] = k01;
        key2[2 * g + 1][pidx] = k23;
    }
    __syncthreads();

    // ---- final: top-100 of {half-1 keys U half-0 candidates}; filter; mean ----
    {
        unsigned int pk[32];
        #pragma unroll
        for (int qd = 0; qd < 8; ++qd) {
            const uint4 v = *(const uint4*)&key2[rp][(lane << 5) + ((qd ^ (lane & 7)) << 2)];
            const unsigned int cb = (unsigned)(2048 + (lane << 5) + 4 * qd);
            pk[4 * qd + 0] = ((par ? (v.x >> 16) : (v.x & 0xFFFFu)) << 12) | (cb + 0);
            pk[4 * qd + 1] = ((par ? (v.y >> 16) : (v.y & 0xFFFFu)) << 12) | (cb + 1);
            pk[4 * qd + 2] = ((par ? (v.z >> 16) : (v.z & 0xFFFFu)) << 12) | (cb + 2);
            pk[4 * qd + 3] = ((par ? (v.w >> 16) : (v.w & 0xFFFFu)) << 12) | (cb + 3);
        }
        const unsigned int c0 = candL[w][lane];
        const unsigned int c1 = (lane < NTOPK - 64) ? candL[w][64 + lane] : 0xFFFFFFFFu;

        // packed values unique -> tie-free exact 100th smallest (bits 25..0)
        unsigned int Ks = 0x4000u << 12;
        #pragma unroll 1
        for (int bit = 25; bit >= 0; --bit) {
            const unsigned int T = Ks | (1u << bit);
            int c = 0;
            #pragma unroll
            for (int j = 0; j < 32; ++j)
                c += __popcll(__ballot(pk[j] < T));
            c += __popcll(__ballot(c0 < T));
            c += __popcll(__ballot(c1 < T));
            if (c < NTOPK) Ks = T;
        }

        const float dpos = 1.0f - cpp[w];
        const int pg = p0 + w;
        const float2 gp = *(const float2*)&G[((size_t)b * NHW + pg) * 2];
        const float px = gp.x * 4096.f, py = gp.y * 4096.f;
        const float base_add = dpos + (FMARGIN - 1.0f);

        float fl = 0.f; int ccnt = 0;
        #pragma unroll
        for (int j = 0; j < 34; ++j) {
            const unsigned int pv8 = (j < 32) ? pk[j] : (j == 32 ? c0 : c1);
            if (pv8 <= Ks) {
                const int q = (int)(pv8 & 4095u);
                bool keep = (q != pg);
                if (keep) {
                    float2 g2 = *(const float2*)&G[((size_t)b * NHW + q) * 2];
                    float dx = fabsf(g2.x * 4096.f - px), dy = fabsf(g2.y * 4096.f - py);
                    keep = !((dx < 1.2f) && (dy < 1.2f));
                }
                if (keep) { fl += base_add + k16tof(pv8 >> 12); ccnt++; }
            }
        }
        #pragma unroll
        for (int d = 1; d < 64; d <<= 1) {
            fl += __shfl_xor(fl, d, 64);
            ccnt += __shfl_xor(ccnt, d, 64);
        }
        if (lane == 0) {
            const int pv = (pvalid[b * NHW + pg] != 0) && (ccnt > 0);
            row_val[b * NHW + pg] = pv ? (fl / (float)ccnt) : 0.f;
            row_valid[b * NHW + pg] = pv;
        }
    }
}

// ---- final deterministic reduction ----
__global__ void k_reduce(const float* __restrict__ row_val, const int* __restrict__ row_valid,
                         float* __restrict__ out) {
    __shared__ float ss[256];
    __shared__ int sc[256];
    float s = 0.f; int n = 0;
    for (int i = threadIdx.x; i < NB * NHW; i += 256) { s += row_val[i]; n += row_valid[i]; }
    ss[threadIdx.x] = s; sc[threadIdx.x] = n;
    __syncthreads();
    for (int d = 128; d > 0; d >>= 1) {
        if (threadIdx.x < d) { ss[threadIdx.x] += ss[threadIdx.x + d]; sc[threadIdx.x] += sc[threadIdx.x + d]; }
        __syncthreads();
    }
    if (threadIdx.x == 0) out[0] = ss[0] / (1e-6f + (float)sc[0]);
}

extern "C" void kernel_launch(void* const* d_in, const int* in_sizes, int n_in,
                              void* d_out, int out_size, void* d_ws, size_t ws_size,
                              hipStream_t stream) {
    const float* sk = (const float*)d_in[0];
    const float* rf = (const float*)d_in[1];
    const float* G  = (const float*)d_in[2];
    char* ws = (char*)d_ws;
    const size_t PANEL8 = (size_t)NB * NC * NHW;      // 4 MB (fp8)
    int*   ac  = (int*)  (ws + 0 * 65536);
    int*   pv  = (int*)  (ws + 1 * 65536);
    float* rv_ = (float*)(ws + 2 * 65536);
    int*   rvd = (int*)  (ws + 3 * 65536);
    unsigned char* rf8 = (unsigned char*)(ws + 4 * 65536);
    unsigned char* sk8 = (unsigned char*)(ws + 4 * 65536 + PANEL8);

    hipLaunchKernelGGL(k_anchor, dim3(64), dim3(256), 0, stream, G, ac, pv);
    hipLaunchKernelGGL(k_packB, dim3(256), dim3(256), 0, stream, rf, rf8);
    hipLaunchKernelGGL(k_packA, dim3(256), dim3(256), 0, stream, sk, sk8);
    hipLaunchKernelGGL(k_main, dim3(1024), dim3(1024), 0, stream,
                       rf8, sk8, G, ac, pv, rv_, rvd);
    hipLaunchKernelGGL(k_reduce, dim3(1), dim3(256), 0, stream, rv_, rvd, (float*)d_out);
}